// Round 5
// baseline (1156.358 us; speedup 1.0000x reference)
//
#include <hip/hip_runtime.h>

typedef _Float16 h16;
typedef _Float16 half4 __attribute__((ext_vector_type(4)));
typedef _Float16 half8 __attribute__((ext_vector_type(8)));
typedef float floatx4 __attribute__((ext_vector_type(4)));

#define B_TOT 1024
#define T_STEPS 24
#define F 64          // FILTERS
#define C2 128        // 2*FILTERS
#define FEAT 15
#define L_ENC 168
#define R 16          // batch rows per tile (= MFMA N dim in swapped form)
#define FP 72         // padded row stride (h16), 144B: 16B-aligned rows, 2-way-bank-free

// ws layout (h16 element offsets)
#define OFF_W5 0          // 12*8*64*8 = 49152
#define OFF_W2 49152      // 16*64*8 = 8192
#define OFF_W3 57344
#define OFF_W4 65536
#define OFF_W1 73728      // 4*64*8 = 2048
#define OFF_B1 75776      // 64
#define OFF_B2 75840      // 128
#define OFF_B4 75968      // 128
#define OFF_B5 76096      // 128
#define OFF_W6 76224      // 128  (total 76352 h16 = 152704 B)

__device__ __forceinline__ floatx4 mfma16(half8 a, half8 b, floatx4 c) {
  return __builtin_amdgcn_mfma_f32_16x16x32_f16(a, b, c, 0, 0, 0);
}

#define PIN(x) asm volatile("" : "+v"(x))

// tanh via exp2+rcp; clamp only the overflow side (x<-44 would inf the exp2)
__device__ __forceinline__ float tanh_fast(float x) {
  float cx = fmaxf(x, -30.f);
  float e  = __builtin_amdgcn_exp2f(-2.885390081777927f * cx);   // e^{-2x}
  return (1.f - e) * __builtin_amdgcn_rcpf(1.f + e);
}
// tanh(f)*sigmoid(g) with one rcp; overflow-side clamps only
__device__ __forceinline__ float gate_fast(float f, float g) {
  float ef = __builtin_amdgcn_exp2f(-2.885390081777927f * fmaxf(f, -30.f));
  float eg = __builtin_amdgcn_exp2f(-1.4426950408889634f * fmaxf(g, -80.f));
  return (1.f - ef) * __builtin_amdgcn_rcpf((1.f + ef) * (1.f + eg));
}

// Pack ALL weights/biases into f16 fragment layout in ws.
// Frag value convention (swapped-MFMA A-operand, m89-verified layout):
//   frag[(kt*8+nt)*64+lane][j] = W[kt*32+(lane>>4)*8+j][nt*16+(lane&15)]
__global__ void prep_pack(const float* __restrict__ W1, const float* __restrict__ b1,
                          const float* __restrict__ W2, const float* __restrict__ b2,
                          const float* __restrict__ W3, const float* __restrict__ W4,
                          const float* __restrict__ b4, const float* __restrict__ W5,
                          const float* __restrict__ b5, const float* __restrict__ W6,
                          h16* __restrict__ ws) {
  int t = blockIdx.x * 256 + threadIdx.x;
  if (t < 6144) {                       // W5: ktg = 2*layer + kt, 12 ktg
    int lane = t & 63, nt = (t >> 6) & 7, ktg = t >> 9;
    int n = nt * 16 + (lane & 15), kb = ktg * 32 + (lane >> 4) * 8;
    half8 v;
    #pragma unroll
    for (int j = 0; j < 8; ++j) v[j] = (h16)W5[(size_t)(kb + j) * C2 + n];
    *(half8*)&ws[(size_t)t * 8] = v;
  } else if (t < 9216) {                // W2/W3/W4
    int u = t - 6144, sel = u >> 10, r = u & 1023;
    int lane = r & 63, nt = (r >> 6) & 7, kt = r >> 9;
    const float* W = (sel == 0) ? W2 : (sel == 1) ? W3 : W4;
    int n = nt * 16 + (lane & 15), kb = kt * 32 + (lane >> 4) * 8;
    half8 v;
    #pragma unroll
    for (int j = 0; j < 8; ++j) v[j] = (h16)W[(size_t)(kb + j) * C2 + n];
    *(half8*)&ws[OFF_W2 + sel * 8192 + (size_t)r * 8] = v;
  } else if (t < 9472) {                // W1 (k>=16 zero-padded), 16x64
    int u = t - 9216, lane = u & 63, nt = u >> 6;
    int n = nt * 16 + (lane & 15);
    half8 v;
    #pragma unroll
    for (int j = 0; j < 8; ++j) {
      int k = (lane >> 4) * 8 + j;
      v[j] = (k < 16) ? (h16)W1[k * F + n] : (h16)0.0f;
    }
    *(half8*)&ws[OFF_W1 + (size_t)u * 8] = v;
  } else if (t < 10048) {               // biases + W6 as raw f16 arrays
    int u = t - 9472;
    h16 v; int off;
    if (u < 64)       { v = (h16)b1[u];        off = OFF_B1 + u; }
    else if (u < 192) { v = (h16)b2[u - 64];   off = OFF_B2 + (u - 64); }
    else if (u < 320) { v = (h16)b4[u - 192];  off = OFF_B4 + (u - 192); }
    else if (u < 448) { v = (h16)b5[u - 320];  off = OFF_B5 + (u - 320); }
    else              { v = (h16)W6[u - 448];  off = OFF_W6 + (u - 448); }
    ws[off] = v;
  }
}

// v11: single-wave-per-tile, ZERO barriers.
// 64 blocks x 64 threads; each wave computes the ENTIRE 16-batch tile step
// (all 8 n-tiles of every matmul). All transposes are in-wave LDS write->
// lgkmcnt->read turnarounds (compiler-ordered); ring/x/gated/skip are private
// to the wave. Weights W1/W2/W3/W4 pinned in VGPRs (1 wave/SIMD -> 512-reg
// budget); W5 frags single-buffered, prefetched one layer ahead from L2;
// stat (t<d) encoder reads prefetched one layer ahead. y recurrence is fully
// in-register (shuffle-reduce, no LDS).
__global__ __launch_bounds__(64, 1) void decoder_v11(
    const float* __restrict__ dec_feat,   // (B,24,15)
    const float* __restrict__ dec_init,   // (B,1)
    const float* __restrict__ enc,        // (6,B,168,64)
    const h16*  __restrict__ ws,
    const float* __restrict__ gb6,
    float* __restrict__ out)              // (B,24)
{
  __shared__ alignas(16) h16 ringL[31][R][FP];  // layer i slots at base 2^i-1
  __shared__ alignas(16) h16 xS[R][FP];
  __shared__ alignas(16) h16 gatedS[R][FP];
  __shared__ alignas(16) h16 skipS[R][FP];

  const int lane = threadIdx.x;
  const int m16  = lane & 15;     // batch row (output col of swapped MFMA)
  const int q    = lane >> 4;
  const int q8   = q * 8;
  const int b0   = blockIdx.x * R;
  const floatx4 z4 = {0.f, 0.f, 0.f, 0.f};

  // ---- weights -> registers ----
  half8 rW2[8][2], rW3[8][2], rW4[8][2], rW1[4];
  #pragma unroll
  for (int nt = 0; nt < 8; ++nt)
    #pragma unroll
    for (int kt = 0; kt < 2; ++kt) {
      int idx = ((kt * 8 + nt) * 64 + lane) * 8;
      rW2[nt][kt] = *(const half8*)&ws[OFF_W2 + idx];
      rW3[nt][kt] = *(const half8*)&ws[OFF_W3 + idx];
      rW4[nt][kt] = *(const half8*)&ws[OFF_W4 + idx];
    }
  #pragma unroll
  for (int nt = 0; nt < 4; ++nt) rW1[nt] = *(const half8*)&ws[OFF_W1 + (nt * 64 + lane) * 8];
  half4 b1h[4], b2h[8], b4h[8];
  #pragma unroll
  for (int nt = 0; nt < 4; ++nt) b1h[nt] = *(const half4*)&ws[OFF_B1 + nt * 16 + q * 4];
  #pragma unroll
  for (int nt = 0; nt < 8; ++nt) {
    b2h[nt] = *(const half4*)&ws[OFF_B2 + nt * 16 + q * 4];
    b4h[nt] = *(const half4*)&ws[OFF_B4 + nt * 16 + q * 4];
  }
  half8 w5f[2][8];                                  // layer-0 chunk initially
  #pragma unroll
  for (int kt = 0; kt < 2; ++kt)
    #pragma unroll
    for (int nt = 0; nt < 8; ++nt)
      w5f[kt][nt] = *(const half8*)&ws[OFF_W5 + ((kt * 8 + nt) * 64 + lane) * 8];

  const float rb6 = gb6[0];
  float yv = dec_init[b0 + m16];                    // y_{-1}, all lanes

  const int DD[6]    = {1, 2, 4, 8, 16, 32};
  const int DBASE[6] = {0, 1, 3, 7, 15, 0};

  // t=0 layer-0 stat prefetch (always encoder at t=0): enc[0][b][L-1][:]
  float4 e0[4];
  { const float* ep = enc + (((size_t)0 * B_TOT + b0 + m16) * L_ENC + (L_ENC - 1)) * F + q8;
    e0[0] = *(const float4*)ep;        e0[1] = *(const float4*)(ep + 4);
    e0[2] = *(const float4*)(ep + 32); e0[3] = *(const float4*)(ep + 36); }

  #pragma unroll 1
  for (int t = 0; t < T_STEPS; ++t) {
    // pin hot weights against rematerialization
    #pragma unroll
    for (int nt = 0; nt < 8; ++nt)
      #pragma unroll
      for (int kt = 0; kt < 2; ++kt) { PIN(rW2[nt][kt]); PIN(rW3[nt][kt]); PIN(rW4[nt][kt]); }
    #pragma unroll
    for (int nt = 0; nt < 4; ++nt) PIN(rW1[nt]);

    // decoder features for this step (q<2 lanes only; scalar dword loads)
    float fbuf[8];
    if (q < 2) {
      const float* fp = dec_feat + (size_t)(b0 + m16) * (T_STEPS * FEAT) + t * FEAT;
      if (q == 0) {
        fbuf[0] = 0.f;
        #pragma unroll
        for (int j = 1; j < 8; ++j) fbuf[j] = fp[j - 1];
      } else {
        #pragma unroll
        for (int j = 0; j < 8; ++j) fbuf[j] = fp[7 + j];
      }
    }

    // layer-0 stat
    half8 statc0, statc1;
    if (t == 0) {
      #pragma unroll
      for (int j = 0; j < 4; ++j) { statc0[j] = (h16)e0[0][j]; statc0[4 + j] = (h16)e0[1][j];
                                    statc1[j] = (h16)e0[2][j]; statc1[4 + j] = (h16)e0[3][j]; }
    } else {
      const h16* sr = &ringL[0][m16][0];
      statc0 = *(const half8*)(sr + q8);
      statc1 = *(const half8*)(sr + 32 + q8);
    }

    // ---- W1: x = tanh(W1^T cur^T + b1) ----
    half8 bCur;
    if (q == 0) {
      bCur[0] = (h16)yv;
      #pragma unroll
      for (int j = 1; j < 8; ++j) bCur[j] = (h16)fbuf[j];
    } else if (q == 1) {
      #pragma unroll
      for (int j = 0; j < 8; ++j) bCur[j] = (h16)fbuf[j];
    } else {
      #pragma unroll
      for (int j = 0; j < 8; ++j) bCur[j] = (h16)0.0f;
    }
    floatx4 xr4[4];
    {
      floatx4 aX[4];
      #pragma unroll
      for (int nt = 0; nt < 4; ++nt) aX[nt] = mfma16(rW1[nt], bCur, z4);
      #pragma unroll
      for (int nt = 0; nt < 4; ++nt) {
        half4 xv;
        #pragma unroll
        for (int j = 0; j < 4; ++j) {
          float v = tanh_fast(aX[nt][j] + (float)b1h[nt][j]);
          xr4[nt][j] = v;
          xv[j] = (h16)v;
        }
        *(half4*)&xS[m16][nt * 16 + q * 4] = xv;
      }
    }

    floatx4 hacc[8];
    #pragma unroll
    for (int nt = 0; nt < 8; ++nt) hacc[nt] = z4;

    // ---- 6 dilation layers, fully in-wave ----
    #pragma unroll
    for (int i = 0; i < 6; ++i) {
      const int d = DD[i];
      // x B-frags: layer 0 from xS, else from ring slot of layer i-1 (just written)
      const h16* xrow = (i == 0) ? &xS[m16][0]
                                 : &ringL[DBASE[i - 1] + (t & (DD[i - 1] - 1))][m16][0];
      half8 xB0 = *(const half8*)(xrow + q8);
      half8 xB1 = *(const half8*)(xrow + 32 + q8);

      // phase A: dil^T = W2^T stat^T + W3^T x^T
      floatx4 aD[8];
      #pragma unroll
      for (int nt = 0; nt < 8; ++nt) aD[nt] = mfma16(rW2[nt][0], statc0, z4);
      #pragma unroll
      for (int nt = 0; nt < 8; ++nt) aD[nt] = mfma16(rW2[nt][1], statc1, aD[nt]);

      // prefetch next layer's stat (ring or encoder) under the MFMAs
      half8 stN0, stN1; float4 eN[4]; bool nextEnc = false;
      if (i < 5) {
        if (t >= DD[i + 1]) {
          const h16* sr = &ringL[DBASE[i + 1] + (t & (DD[i + 1] - 1))][m16][0];
          stN0 = *(const half8*)(sr + q8);
          stN1 = *(const half8*)(sr + 32 + q8);
        } else {
          nextEnc = true;
          const float* ep = enc + (((size_t)(i + 1) * B_TOT + b0 + m16) * L_ENC
                                   + (L_ENC + t - DD[i + 1])) * F + q8;
          eN[0] = *(const float4*)ep;        eN[1] = *(const float4*)(ep + 4);
          eN[2] = *(const float4*)(ep + 32); eN[3] = *(const float4*)(ep + 36);
        }
      }

      #pragma unroll
      for (int nt = 0; nt < 8; ++nt) aD[nt] = mfma16(rW3[nt][0], xB0, aD[nt]);
      #pragma unroll
      for (int nt = 0; nt < 8; ++nt) aD[nt] = mfma16(rW3[nt][1], xB1, aD[nt]);

      // gate -> gatedS (f = cols 0..63 / nt 0..3 ; g = cols 64..127 / nt 4..7)
      #pragma unroll
      for (int nt = 0; nt < 4; ++nt) {
        half4 gv;
        #pragma unroll
        for (int j = 0; j < 4; ++j) {
          float f = aD[nt][j]     + (float)b2h[nt][j];
          float g = aD[nt + 4][j] + (float)b2h[nt + 4][j];
          gv[j] = (h16)gate_fast(f, g);
        }
        *(half4*)&gatedS[m16][nt * 16 + q * 4] = gv;
      }
      half8 gB0 = *(const half8*)&gatedS[m16][q8];
      half8 gB1 = *(const half8*)&gatedS[m16][32 + q8];

      // phase B: o^T = W4^T gated^T
      floatx4 oD[8];
      #pragma unroll
      for (int nt = 0; nt < 8; ++nt) oD[nt] = mfma16(rW4[nt][0], gB0, z4);
      #pragma unroll
      for (int nt = 0; nt < 8; ++nt) oD[nt] = mfma16(rW4[nt][1], gB1, oD[nt]);

      // epilogue: skip (cols 0..63) and residual x-update (cols 64..127)
      #pragma unroll
      for (int nt = 0; nt < 4; ++nt) {
        half4 sv;
        #pragma unroll
        for (int j = 0; j < 4; ++j)
          sv[j] = (h16)fmaxf(oD[nt][j] + (float)b4h[nt][j], 0.0f);
        *(half4*)&skipS[m16][nt * 16 + q * 4] = sv;
      }
      if (i < 5) {                                  // layer 5's x-update is dead
        h16* rrow = &ringL[DBASE[i] + (t & (d - 1))][m16][0];
        #pragma unroll
        for (int nt = 0; nt < 4; ++nt) {
          half4 xv2;
          #pragma unroll
          for (int j = 0; j < 4; ++j) {
            float xn = xr4[nt][j] + oD[nt + 4][j] + (float)b4h[nt + 4][j];
            xr4[nt][j] = xn;
            xv2[j] = (h16)xn;
          }
          *(half4*)&rrow[nt * 16 + q * 4] = xv2;
        }
      }
      half8 sk0 = *(const half8*)&skipS[m16][q8];
      half8 sk1 = *(const half8*)&skipS[m16][32 + q8];

      // W5 chunk i
      #pragma unroll
      for (int nt = 0; nt < 8; ++nt) hacc[nt] = mfma16(w5f[0][nt], sk0, hacc[nt]);
      #pragma unroll
      for (int nt = 0; nt < 8; ++nt) hacc[nt] = mfma16(w5f[1][nt], sk1, hacc[nt]);

      // prefetch next layer's W5 frags (layer 5 -> next step's layer 0)
      {
        const int ln = (i < 5) ? i + 1 : 0;
        #pragma unroll
        for (int kt = 0; kt < 2; ++kt)
          #pragma unroll
          for (int nt = 0; nt < 8; ++nt)
            w5f[kt][nt] =
                *(const half8*)&ws[OFF_W5 + (((2 * ln + kt) * 8 + nt) * 64 + lane) * 8];
      }

      // stat handoff
      if (i < 5) {
        if (!nextEnc) { statc0 = stN0; statc1 = stN1; }
        else {
          #pragma unroll
          for (int j = 0; j < 4; ++j) {
            statc0[j] = (h16)eN[0][j]; statc0[4 + j] = (h16)eN[1][j];
            statc1[j] = (h16)eN[2][j]; statc1[4 + j] = (h16)eN[3][j];
          }
        }
      }
    }

    // ---- head: y = relu(h + b5) . W6 + b6, in-register reduce ----
    {
      float yacc = 0.f;
      #pragma unroll
      for (int nt = 0; nt < 8; ++nt) {
        half4 b5h = *(const half4*)&ws[OFF_B5 + nt * 16 + q * 4];
        half4 w6h = *(const half4*)&ws[OFF_W6 + nt * 16 + q * 4];
        #pragma unroll
        for (int j = 0; j < 4; ++j)
          yacc += fmaxf(hacc[nt][j] + (float)b5h[j], 0.0f) * (float)w6h[j];
      }
      yacc += __shfl_xor(yacc, 16);
      yacc += __shfl_xor(yacc, 32);
      yv = yacc + rb6;
      if (q == 0) out[(size_t)(b0 + m16) * T_STEPS + t] = yv;   // fire-and-forget
    }
  }
}

extern "C" void kernel_launch(void* const* d_in, const int* in_sizes, int n_in,
                              void* d_out, int out_size, void* d_ws, size_t ws_size,
                              hipStream_t stream) {
  const float* dec_feat = (const float*)d_in[0];
  const float* dec_init = (const float*)d_in[1];
  const float* enc      = (const float*)d_in[2];
  const float* W1 = (const float*)d_in[3];
  const float* b1 = (const float*)d_in[4];
  const float* W2 = (const float*)d_in[5];
  const float* b2 = (const float*)d_in[6];
  const float* W3 = (const float*)d_in[7];
  const float* W4 = (const float*)d_in[8];
  const float* b4 = (const float*)d_in[9];
  const float* W5 = (const float*)d_in[10];
  const float* b5 = (const float*)d_in[11];
  const float* W6 = (const float*)d_in[12];
  const float* b6 = (const float*)d_in[13];
  float* out = (float*)d_out;
  h16* wsp = (h16*)d_ws;

  prep_pack<<<40, 256, 0, stream>>>(W1, b1, W2, b2, W3, W4, b4, W5, b5, W6, wsp);
  decoder_v11<<<dim3(B_TOT / R), dim3(64), 0, stream>>>(
      dec_feat, dec_init, enc, wsp, b6, out);
}

// Round 6
// 923.854 us; speedup vs baseline: 1.2517x; 1.2517x over previous
//
#include <hip/hip_runtime.h>

typedef _Float16 h16;
typedef _Float16 half4 __attribute__((ext_vector_type(4)));
typedef _Float16 half8 __attribute__((ext_vector_type(8)));
typedef float floatx4 __attribute__((ext_vector_type(4)));

#define B_TOT 1024
#define T_STEPS 24
#define F 64          // FILTERS
#define C2 128        // 2*FILTERS
#define FEAT 15
#define L_ENC 168
#define R 16          // batch rows per tile (= MFMA N dim in swapped form)
#define FP 72         // padded row stride (h16)

// ws layout (h16 element offsets)
#define OFF_W5 0          // 12*8*64*8 = 49152
#define OFF_W2 49152      // 16*64*8 = 8192
#define OFF_W3 57344
#define OFF_W4 65536
#define OFF_W1 73728      // 4*64*8 = 2048
#define OFF_B1 75776      // 64
#define OFF_B2 75840      // 128
#define OFF_B4 75968      // 128
#define OFF_B5 76096      // 128
#define OFF_W6 76224      // 128  (total 76352 h16 = 152704 B)

__device__ __forceinline__ floatx4 mfma16(half8 a, half8 b, floatx4 c) {
  return __builtin_amdgcn_mfma_f32_16x16x32_f16(a, b, c, 0, 0, 0);
}

// AGPR pin: forces residency in the accumulator register file (MFMA reads
// A/B/C from AGPRs directly on gfx950), freeing arch VGPRs. This is the fix
// for v11's spills (VGPR_Count=256 + 5MB scratch writes).
#define PINA(x) asm volatile("" : "+a"(x))

// tanh via exp2+rcp; clamp only the overflow side
__device__ __forceinline__ float tanh_fast(float x) {
  float cx = fmaxf(x, -30.f);
  float e  = __builtin_amdgcn_exp2f(-2.885390081777927f * cx);   // e^{-2x}
  return (1.f - e) * __builtin_amdgcn_rcpf(1.f + e);
}
__device__ __forceinline__ float gate_fast(float f, float g) {
  float ef = __builtin_amdgcn_exp2f(-2.885390081777927f * fmaxf(f, -30.f));
  float eg = __builtin_amdgcn_exp2f(-1.4426950408889634f * fmaxf(g, -80.f));
  return (1.f - ef) * __builtin_amdgcn_rcpf((1.f + ef) * (1.f + eg));
}

// Pack ALL weights/biases into f16 fragment layout in ws.
// frag[(kt*8+nt)*64+lane][j] = W[kt*32+(lane>>4)*8+j][nt*16+(lane&15)]
__global__ void prep_pack(const float* __restrict__ W1, const float* __restrict__ b1,
                          const float* __restrict__ W2, const float* __restrict__ b2,
                          const float* __restrict__ W3, const float* __restrict__ W4,
                          const float* __restrict__ b4, const float* __restrict__ W5,
                          const float* __restrict__ b5, const float* __restrict__ W6,
                          h16* __restrict__ ws) {
  int t = blockIdx.x * 256 + threadIdx.x;
  if (t < 6144) {                       // W5: ktg = 2*layer + kt
    int lane = t & 63, nt = (t >> 6) & 7, ktg = t >> 9;
    int n = nt * 16 + (lane & 15), kb = ktg * 32 + (lane >> 4) * 8;
    half8 v;
    #pragma unroll
    for (int j = 0; j < 8; ++j) v[j] = (h16)W5[(size_t)(kb + j) * C2 + n];
    *(half8*)&ws[(size_t)t * 8] = v;
  } else if (t < 9216) {                // W2/W3/W4
    int u = t - 6144, sel = u >> 10, r = u & 1023;
    int lane = r & 63, nt = (r >> 6) & 7, kt = r >> 9;
    const float* W = (sel == 0) ? W2 : (sel == 1) ? W3 : W4;
    int n = nt * 16 + (lane & 15), kb = kt * 32 + (lane >> 4) * 8;
    half8 v;
    #pragma unroll
    for (int j = 0; j < 8; ++j) v[j] = (h16)W[(size_t)(kb + j) * C2 + n];
    *(half8*)&ws[OFF_W2 + sel * 8192 + (size_t)r * 8] = v;
  } else if (t < 9472) {                // W1 (k>=16 zero-padded)
    int u = t - 9216, lane = u & 63, nt = u >> 6;
    int n = nt * 16 + (lane & 15);
    half8 v;
    #pragma unroll
    for (int j = 0; j < 8; ++j) {
      int k = (lane >> 4) * 8 + j;
      v[j] = (k < 16) ? (h16)W1[k * F + n] : (h16)0.0f;
    }
    *(half8*)&ws[OFF_W1 + (size_t)u * 8] = v;
  } else if (t < 10048) {               // biases + W6
    int u = t - 9472;
    h16 v; int off;
    if (u < 64)       { v = (h16)b1[u];        off = OFF_B1 + u; }
    else if (u < 192) { v = (h16)b2[u - 64];   off = OFF_B2 + (u - 64); }
    else if (u < 320) { v = (h16)b4[u - 192];  off = OFF_B4 + (u - 192); }
    else if (u < 448) { v = (h16)b5[u - 320];  off = OFF_B5 + (u - 320); }
    else              { v = (h16)W6[u - 448];  off = OFF_W6 + (u - 448); }
    ws[off] = v;
  }
}

// v12: v11's zero-barrier single-wave design with the register file split:
//  - W1/W2/W3/W4 frags (104 regs), hacc (32), head b5/W6 quads (16) pinned
//    into AGPRs; MFMA consumes them directly. Arch-VGPR peak ~190 -> no spill.
//  - W5 frags loaded per-layer at layer TOP (L2-hot), consumed at layer
//    bottom (~600cy later) -> latency hidden, no cross-layer residency.
//  - dec_feat prefetched one step ahead; t=0 stat pre-converted to h16.
__global__ __launch_bounds__(64, 1) void decoder_v12(
    const float* __restrict__ dec_feat,   // (B,24,15)
    const float* __restrict__ dec_init,   // (B,1)
    const float* __restrict__ enc,        // (6,B,168,64)
    const h16*  __restrict__ ws,
    const float* __restrict__ gb6,
    float* __restrict__ out)              // (B,24)
{
  __shared__ alignas(16) h16 ringL[31][R][FP];  // layer i slots at base 2^i-1
  __shared__ alignas(16) h16 xS[R][FP];
  __shared__ alignas(16) h16 gatedS[R][FP];
  __shared__ alignas(16) h16 skipS[R][FP];

  const int lane = threadIdx.x;
  const int m16  = lane & 15;     // batch row
  const int q    = lane >> 4;
  const int q8   = q * 8;
  const int b0   = blockIdx.x * R;
  const floatx4 z4 = {0.f, 0.f, 0.f, 0.f};

  // ---- stationary weights -> AGPRs ----
  half8 rW2[8][2], rW3[8][2], rW4[8][2], rW1[4];
  #pragma unroll
  for (int nt = 0; nt < 8; ++nt)
    #pragma unroll
    for (int kt = 0; kt < 2; ++kt) {
      int idx = ((kt * 8 + nt) * 64 + lane) * 8;
      rW2[nt][kt] = *(const half8*)&ws[OFF_W2 + idx];
      rW3[nt][kt] = *(const half8*)&ws[OFF_W3 + idx];
      rW4[nt][kt] = *(const half8*)&ws[OFF_W4 + idx];
      PINA(rW2[nt][kt]); PINA(rW3[nt][kt]); PINA(rW4[nt][kt]);
    }
  #pragma unroll
  for (int nt = 0; nt < 4; ++nt) {
    rW1[nt] = *(const half8*)&ws[OFF_W1 + (nt * 64 + lane) * 8];
    PINA(rW1[nt]);
  }
  // biases (h16 quads, arch VGPRs - small)
  half4 b1h[4], b2h[8], b4h[8], b5h[8], w6h[8];
  #pragma unroll
  for (int nt = 0; nt < 4; ++nt) b1h[nt] = *(const half4*)&ws[OFF_B1 + nt * 16 + q * 4];
  #pragma unroll
  for (int nt = 0; nt < 8; ++nt) {
    b2h[nt] = *(const half4*)&ws[OFF_B2 + nt * 16 + q * 4];
    b4h[nt] = *(const half4*)&ws[OFF_B4 + nt * 16 + q * 4];
    b5h[nt] = *(const half4*)&ws[OFF_B5 + nt * 16 + q * 4];
    w6h[nt] = *(const half4*)&ws[OFF_W6 + nt * 16 + q * 4];
    PINA(b5h[nt]); PINA(w6h[nt]);
  }

  const float rb6 = gb6[0];
  float yv = dec_init[b0 + m16];                    // y_{-1}, all lanes

  const int DD[6]    = {1, 2, 4, 8, 16, 32};
  const int DBASE[6] = {0, 1, 3, 7, 15, 0};

  // t=0 layer-0 stat, pre-converted to h16 (8 regs, not 16)
  half8 st00, st01;
  { const float* ep = enc + (((size_t)0 * B_TOT + b0 + m16) * L_ENC + (L_ENC - 1)) * F + q8;
    float4 a0 = *(const float4*)ep,        a1 = *(const float4*)(ep + 4);
    float4 a2 = *(const float4*)(ep + 32), a3 = *(const float4*)(ep + 36);
    #pragma unroll
    for (int j = 0; j < 4; ++j) { st00[j] = (h16)a0[j]; st00[4 + j] = (h16)a1[j];
                                  st01[j] = (h16)a2[j]; st01[4 + j] = (h16)a3[j]; } }
  // step-0 features
  float fbuf[8];
  if (q < 2) {
    const float* fp = dec_feat + (size_t)(b0 + m16) * (T_STEPS * FEAT);
    if (q == 0) { fbuf[0] = 0.f;
      #pragma unroll
      for (int j = 1; j < 8; ++j) fbuf[j] = fp[j - 1];
    } else {
      #pragma unroll
      for (int j = 0; j < 8; ++j) fbuf[j] = fp[7 + j];
    }
  }

  #pragma unroll 1
  for (int t = 0; t < T_STEPS; ++t) {
    // re-pin stationaries each iteration (keeps them in AGPRs, no remat)
    #pragma unroll
    for (int nt = 0; nt < 8; ++nt)
      #pragma unroll
      for (int kt = 0; kt < 2; ++kt) { PINA(rW2[nt][kt]); PINA(rW3[nt][kt]); PINA(rW4[nt][kt]); }
    #pragma unroll
    for (int nt = 0; nt < 4; ++nt) PINA(rW1[nt]);

    // layer-0 stat
    half8 statc0, statc1;
    if (t == 0) { statc0 = st00; statc1 = st01; }
    else {
      const h16* sr = &ringL[0][m16][0];
      statc0 = *(const half8*)(sr + q8);
      statc1 = *(const half8*)(sr + 32 + q8);
    }

    // ---- W1: x = tanh(W1^T cur^T + b1) ----
    half8 bCur;
    if (q == 0) {
      bCur[0] = (h16)yv;
      #pragma unroll
      for (int j = 1; j < 8; ++j) bCur[j] = (h16)fbuf[j];
    } else if (q == 1) {
      #pragma unroll
      for (int j = 0; j < 8; ++j) bCur[j] = (h16)fbuf[j];
    } else {
      #pragma unroll
      for (int j = 0; j < 8; ++j) bCur[j] = (h16)0.0f;
    }
    floatx4 xr4[4];
    {
      floatx4 aX[4];
      #pragma unroll
      for (int nt = 0; nt < 4; ++nt) aX[nt] = mfma16(rW1[nt], bCur, z4);
      #pragma unroll
      for (int nt = 0; nt < 4; ++nt) {
        half4 xv;
        #pragma unroll
        for (int j = 0; j < 4; ++j) {
          float v = tanh_fast(aX[nt][j] + (float)b1h[nt][j]);
          xr4[nt][j] = v;
          xv[j] = (h16)v;
        }
        *(half4*)&xS[m16][nt * 16 + q * 4] = xv;
      }
    }
    // prefetch next step's features (consumed next iteration)
    if (q < 2 && t + 1 < T_STEPS) {
      const float* fp = dec_feat + (size_t)(b0 + m16) * (T_STEPS * FEAT) + (t + 1) * FEAT;
      if (q == 0) { fbuf[0] = 0.f;
        #pragma unroll
        for (int j = 1; j < 8; ++j) fbuf[j] = fp[j - 1];
      } else {
        #pragma unroll
        for (int j = 0; j < 8; ++j) fbuf[j] = fp[7 + j];
      }
    }

    floatx4 hacc[8];
    #pragma unroll
    for (int nt = 0; nt < 8; ++nt) { hacc[nt] = z4; PINA(hacc[nt]); }

    // ---- 6 dilation layers, fully in-wave, zero barriers ----
    #pragma unroll
    for (int i = 0; i < 6; ++i) {
      const int d = DD[i];
      const h16* xrow = (i == 0) ? &xS[m16][0]
                                 : &ringL[DBASE[i - 1] + (t & (DD[i - 1] - 1))][m16][0];
      half8 xB0 = *(const half8*)(xrow + q8);
      half8 xB1 = *(const half8*)(xrow + 32 + q8);

      // issue W5 chunk-i loads NOW (L2-hot; consumed ~600cy later at W5 MFMAs)
      half8 w5f[2][8];
      #pragma unroll
      for (int kt = 0; kt < 2; ++kt)
        #pragma unroll
        for (int nt = 0; nt < 8; ++nt)
          w5f[kt][nt] =
              *(const half8*)&ws[OFF_W5 + (((2 * i + kt) * 8 + nt) * 64 + lane) * 8];

      // phase A: dil^T = W2^T stat^T + W3^T x^T
      floatx4 aD[8];
      #pragma unroll
      for (int nt = 0; nt < 8; ++nt) aD[nt] = mfma16(rW2[nt][0], statc0, z4);
      #pragma unroll
      for (int nt = 0; nt < 8; ++nt) aD[nt] = mfma16(rW2[nt][1], statc1, aD[nt]);

      // prefetch next layer's stat under the MFMAs
      half8 stN0, stN1; float4 eN[4]; bool nextEnc = false;
      if (i < 5) {
        if (t >= DD[i + 1]) {
          const h16* sr = &ringL[DBASE[i + 1] + (t & (DD[i + 1] - 1))][m16][0];
          stN0 = *(const half8*)(sr + q8);
          stN1 = *(const half8*)(sr + 32 + q8);
        } else {
          nextEnc = true;
          const float* ep = enc + (((size_t)(i + 1) * B_TOT + b0 + m16) * L_ENC
                                   + (L_ENC + t - DD[i + 1])) * F + q8;
          eN[0] = *(const float4*)ep;        eN[1] = *(const float4*)(ep + 4);
          eN[2] = *(const float4*)(ep + 32); eN[3] = *(const float4*)(ep + 36);
        }
      }

      #pragma unroll
      for (int nt = 0; nt < 8; ++nt) aD[nt] = mfma16(rW3[nt][0], xB0, aD[nt]);
      #pragma unroll
      for (int nt = 0; nt < 8; ++nt) aD[nt] = mfma16(rW3[nt][1], xB1, aD[nt]);

      // gate -> gatedS
      #pragma unroll
      for (int nt = 0; nt < 4; ++nt) {
        half4 gv;
        #pragma unroll
        for (int j = 0; j < 4; ++j) {
          float f = aD[nt][j]     + (float)b2h[nt][j];
          float g = aD[nt + 4][j] + (float)b2h[nt + 4][j];
          gv[j] = (h16)gate_fast(f, g);
        }
        *(half4*)&gatedS[m16][nt * 16 + q * 4] = gv;
      }
      half8 gB0 = *(const half8*)&gatedS[m16][q8];
      half8 gB1 = *(const half8*)&gatedS[m16][32 + q8];

      // phase B: o^T = W4^T gated^T
      floatx4 oD[8];
      #pragma unroll
      for (int nt = 0; nt < 8; ++nt) oD[nt] = mfma16(rW4[nt][0], gB0, z4);
      #pragma unroll
      for (int nt = 0; nt < 8; ++nt) oD[nt] = mfma16(rW4[nt][1], gB1, oD[nt]);

      // epilogue: skip + residual x-update
      #pragma unroll
      for (int nt = 0; nt < 4; ++nt) {
        half4 sv;
        #pragma unroll
        for (int j = 0; j < 4; ++j)
          sv[j] = (h16)fmaxf(oD[nt][j] + (float)b4h[nt][j], 0.0f);
        *(half4*)&skipS[m16][nt * 16 + q * 4] = sv;
      }
      if (i < 5) {
        h16* rrow = &ringL[DBASE[i] + (t & (d - 1))][m16][0];
        #pragma unroll
        for (int nt = 0; nt < 4; ++nt) {
          half4 xv2;
          #pragma unroll
          for (int j = 0; j < 4; ++j) {
            float xn = xr4[nt][j] + oD[nt + 4][j] + (float)b4h[nt + 4][j];
            xr4[nt][j] = xn;
            xv2[j] = (h16)xn;
          }
          *(half4*)&rrow[nt * 16 + q * 4] = xv2;
        }
      }
      half8 sk0 = *(const half8*)&skipS[m16][q8];
      half8 sk1 = *(const half8*)&skipS[m16][32 + q8];

      // W5 chunk i
      #pragma unroll
      for (int nt = 0; nt < 8; ++nt) hacc[nt] = mfma16(w5f[0][nt], sk0, hacc[nt]);
      #pragma unroll
      for (int nt = 0; nt < 8; ++nt) hacc[nt] = mfma16(w5f[1][nt], sk1, hacc[nt]);

      // stat handoff
      if (i < 5) {
        if (!nextEnc) { statc0 = stN0; statc1 = stN1; }
        else {
          #pragma unroll
          for (int j = 0; j < 4; ++j) {
            statc0[j] = (h16)eN[0][j]; statc0[4 + j] = (h16)eN[1][j];
            statc1[j] = (h16)eN[2][j]; statc1[4 + j] = (h16)eN[3][j];
          }
        }
      }
    }

    // ---- head: y = relu(h + b5) . W6 + b6 ----
    {
      float yacc = 0.f;
      #pragma unroll
      for (int nt = 0; nt < 8; ++nt) {
        #pragma unroll
        for (int j = 0; j < 4; ++j)
          yacc += fmaxf(hacc[nt][j] + (float)b5h[nt][j], 0.0f) * (float)w6h[nt][j];
      }
      yacc += __shfl_xor(yacc, 16);
      yacc += __shfl_xor(yacc, 32);
      yv = yacc + rb6;
      if (q == 0) out[(size_t)(b0 + m16) * T_STEPS + t] = yv;   // fire-and-forget
    }
  }
}

extern "C" void kernel_launch(void* const* d_in, const int* in_sizes, int n_in,
                              void* d_out, int out_size, void* d_ws, size_t ws_size,
                              hipStream_t stream) {
  const float* dec_feat = (const float*)d_in[0];
  const float* dec_init = (const float*)d_in[1];
  const float* enc      = (const float*)d_in[2];
  const float* W1 = (const float*)d_in[3];
  const float* b1 = (const float*)d_in[4];
  const float* W2 = (const float*)d_in[5];
  const float* b2 = (const float*)d_in[6];
  const float* W3 = (const float*)d_in[7];
  const float* W4 = (const float*)d_in[8];
  const float* b4 = (const float*)d_in[9];
  const float* W5 = (const float*)d_in[10];
  const float* b5 = (const float*)d_in[11];
  const float* W6 = (const float*)d_in[12];
  const float* b6 = (const float*)d_in[13];
  float* out = (float*)d_out;
  h16* wsp = (h16*)d_ws;

  prep_pack<<<40, 256, 0, stream>>>(W1, b1, W2, b2, W3, W4, b4, W5, b5, W6, wsp);
  decoder_v12<<<dim3(B_TOT / R), dim3(64), 0, stream>>>(
      dec_feat, dec_init, enc, wsp, b6, out);
}

// Round 7
// 452.131 us; speedup vs baseline: 2.5576x; 2.0433x over previous
//
#include <hip/hip_runtime.h>

typedef _Float16 h16;
typedef _Float16 half4 __attribute__((ext_vector_type(4)));
typedef _Float16 half8 __attribute__((ext_vector_type(8)));
typedef float floatx4 __attribute__((ext_vector_type(4)));

#define B_TOT 1024
#define T_STEPS 24
#define F 64          // FILTERS
#define C2 128        // 2*FILTERS
#define FEAT 15
#define L_ENC 168
#define R 16          // batch rows per block
#define BLK 256       // 4 waves
#define FP 72         // padded row stride (h16)

// ws byte layout: W5 f16 frags [0, 98304); xFeat f32 [98304, 98304+6291456)
#define WS_XF_BYTE 98304

__device__ __forceinline__ floatx4 mfma16(half8 a, half8 b, floatx4 c) {
  return __builtin_amdgcn_mfma_f32_16x16x32_f16(a, b, c, 0, 0, 0);
}

// LDS-producer barrier: no vmcnt drain -> global prefetches stay in flight.
#define BAR() asm volatile("s_waitcnt lgkmcnt(0)\n\ts_barrier" ::: "memory")

// tanh via exp2+rcp; clamp only the overflow side
__device__ __forceinline__ float tanh_fast(float x) {
  float cx = fmaxf(x, -30.f);
  float e  = __builtin_amdgcn_exp2f(-2.885390081777927f * cx);   // e^{-2x}
  return (1.f - e) * __builtin_amdgcn_rcpf(1.f + e);
}
__device__ __forceinline__ float gate_fast(float f, float g) {
  float ef = __builtin_amdgcn_exp2f(-2.885390081777927f * fmaxf(f, -30.f));
  float eg = __builtin_amdgcn_exp2f(-1.4426950408889634f * fmaxf(g, -80.f));
  return (1.f - ef) * __builtin_amdgcn_rcpf((1.f + ef) * (1.f + eg));
}

// W5 (384x128 f32) -> f16 B-frag layout at ws[0]
__global__ void prep_w5(const float* __restrict__ gW5, h16* __restrict__ wsW5) {
  int t = blockIdx.x * 256 + threadIdx.x;     // 0..6143
  if (t >= 12 * 8 * 64) return;
  int lane = t & 63, nt = (t >> 6) & 7, ktg = t >> 9;
  int n  = nt * 16 + (lane & 15);
  int kb = ktg * 32 + (lane >> 4) * 8;
  half8 v;
  #pragma unroll
  for (int j = 0; j < 8; ++j) v[j] = (h16)gW5[(size_t)(kb + j) * C2 + n];
  *(half8*)&wsW5[(size_t)t * 8] = v;
}

// xFeat[b][t][c] = b1[c] + sum_f h16(feat[b][t][f]) * h16(W1[1+f][c]), f32.
// Numerically matches the old in-loop MFMA path (h16 products, f32 accum).
__global__ void prep_xfeat(const float* __restrict__ df, const float* __restrict__ W1,
                           const float* __restrict__ b1, float* __restrict__ xf) {
  int idx = blockIdx.x * 256 + threadIdx.x;          // B*T*16 = 393216 tasks
  if (idx >= B_TOT * T_STEPS * 16) return;
  int c4 = (idx & 15) * 4;
  int bt = idx >> 4;
  int b  = bt / T_STEPS, t = bt - b * T_STEPS;
  const float* fp = df + (size_t)b * (T_STEPS * FEAT) + t * FEAT;
  float acc[4];
  #pragma unroll
  for (int j = 0; j < 4; ++j) acc[j] = b1[c4 + j];
  #pragma unroll
  for (int f = 0; f < FEAT; ++f) {
    float fv = (float)(h16)fp[f];
    #pragma unroll
    for (int j = 0; j < 4; ++j)
      acc[j] += fv * (float)(h16)W1[(1 + f) * F + c4 + j];
  }
  float* op = xf + ((size_t)b * T_STEPS + t) * F + c4;
  #pragma unroll
  for (int j = 0; j < 4; ++j) op[j] = acc[j];
}

// v13 = v10 (best verified, 4-wave filter-sharded) +
//  - B1 eliminated: x0 computed consumer-side from precomputed xFeat (f32, ws)
//    + w1y*y + tanh; no W1 MFMA, no xH roundtrip for layer 0. 13 segments/step.
//  - enc fully pre-staged (ring slots + enc5L, v9 mechanics): loadStat pure LDS;
//    zero in-loop enc/dec_feat global reads.
//  - trimmed gate clamps. No register pins (v10's natural allocation was best).
__global__ __launch_bounds__(BLK, 1) void decoder_v13(
    const float* __restrict__ dec_init,   // (B,1)
    const float* __restrict__ enc,        // (6,B,168,64)
    const float* __restrict__ gW1,
    const float* __restrict__ gW2, const float* __restrict__ gb2,
    const float* __restrict__ gW3,
    const float* __restrict__ gW4, const float* __restrict__ gb4,
    const h16*  __restrict__ wsW5, const float* __restrict__ xFeat,
    const float* __restrict__ gb5,
    const float* __restrict__ gW6, const float* __restrict__ gb6,
    float* __restrict__ out)              // (B,24)
{
  __shared__ alignas(16) h16 ringL[31][R][FP];      // 71424B, layer i base 2^i-1
  __shared__ alignas(16) h16 enc5L[T_STEPS][R][FP]; // 55296B, layer-5 stat
  __shared__ alignas(16) h16 xH[R][FP];             // residual stream (layers 1..5 read)
  __shared__ alignas(16) h16 gatedH[R][FP];
  __shared__ alignas(16) h16 skipH[R][FP];
  __shared__ alignas(16) float ypartS[R][4];

  const int tid  = threadIdx.x;
  const int w    = tid >> 6;
  const int lane = tid & 63;
  const int m16  = lane & 15;       // batch row owned (output col of swapped MFMA)
  const int q    = lane >> 4;
  const int q8   = q * 8;
  const int b0   = blockIdx.x * R;
  const int col4 = w * 16 + q * 4;  // first of 4 owned filters

  // ---- loop-invariant weights -> registers (v10 layout) ----
  half8 rW2[2][2], rW3[2][2], rW4[2][2];
  #pragma unroll
  for (int h = 0; h < 2; ++h) {
    int n = (w + 4 * h) * 16 + m16;
    #pragma unroll
    for (int kt = 0; kt < 2; ++kt) {
      half8 v2, v3, v4;
      #pragma unroll
      for (int j = 0; j < 8; ++j) {
        int k = kt * 32 + q8 + j;
        v2[j] = (h16)gW2[k * C2 + n];
        v3[j] = (h16)gW3[k * C2 + n];
        v4[j] = (h16)gW4[k * C2 + n];
      }
      rW2[h][kt] = v2; rW3[h][kt] = v3; rW4[h][kt] = v4;
    }
  }
  half8 w5r[6][4];
  #pragma unroll
  for (int i = 0; i < 6; ++i)
    #pragma unroll
    for (int kt = 0; kt < 2; ++kt)
      #pragma unroll
      for (int nn = 0; nn < 2; ++nn)
        w5r[i][kt * 2 + nn] =
            *(const half8*)&wsW5[(size_t)((((2 * i + kt) * 8) + (w + 4 * nn)) * 64 + lane) * 8];

  // W1 row 0 (the y column), h16-rounded, at consumed + owned cols
  half8 w1h0, w1h1; half4 w1h4;
  #pragma unroll
  for (int j = 0; j < 8; ++j) { w1h0[j] = (h16)gW1[q8 + j]; w1h1[j] = (h16)gW1[32 + q8 + j]; }
  #pragma unroll
  for (int j = 0; j < 4; ++j) w1h4[j] = (h16)gW1[col4 + j];

  floatx4 rb2fv = *(const floatx4*)&gb2[col4];
  floatx4 rb2gv = *(const floatx4*)&gb2[64 + col4];
  floatx4 rb4sv = *(const floatx4*)&gb4[col4];
  floatx4 rb4rv = *(const floatx4*)&gb4[64 + col4];
  floatx4 rb5av = *(const floatx4*)&gb5[col4];
  floatx4 rb5bv = *(const floatx4*)&gb5[64 + col4];
  floatx4 rw6av = *(const floatx4*)&gW6[col4];
  floatx4 rw6bv = *(const floatx4*)&gW6[64 + col4];
  const float rb6   = gb6[0];
  const float rInit = dec_init[b0 + m16];

  // ---- pre-stage encoder tails: ring slots (layers 0..4) + enc5L (layer 5) ----
  {
    int mm = tid >> 4, kk = (tid & 15) * 4;
    #pragma unroll 1
    for (int it = 0; it < 55; ++it) {
      int i, s; h16* dst;
      if (it < 31) {                               // it == (2^i - 1) + s
        i = (it >= 15) ? 4 : (it >= 7) ? 3 : (it >= 3) ? 2 : (it >= 1) ? 1 : 0;
        s = it - ((1 << i) - 1);
        dst = &ringL[it][mm][kk];
      } else { i = 5; s = it - 31; dst = &enc5L[s][mm][kk]; }
      int d = 1 << i;
      const float* sp = enc + (((size_t)i * B_TOT + b0 + mm) * L_ENC + (L_ENC + s - d)) * F + kk;
      float4 v = *(const float4*)sp;
      half4 hv; hv[0] = (h16)v.x; hv[1] = (h16)v.y; hv[2] = (h16)v.z; hv[3] = (h16)v.w;
      *(half4*)dst = hv;
    }
  }
  // xFeat for step 0 (f32, consumed + owned cols)
  const float* xfb = xFeat + (size_t)(b0 + m16) * T_STEPS * F;
  float4 xf0, xf1, xf2, xf3, xf4;
  xf0 = *(const float4*)(xfb + q8);      xf1 = *(const float4*)(xfb + q8 + 4);
  xf2 = *(const float4*)(xfb + 32 + q8); xf3 = *(const float4*)(xfb + 32 + q8 + 4);
  xf4 = *(const float4*)(xfb + col4);
  __syncthreads();

  // pure-LDS stat loader (i compile-time)
  auto loadStat = [&](half8* dst, int i, int t) {
    const h16* p = (i == 5) ? &enc5L[t][m16][0]
                            : &ringL[((1 << i) - 1) + (t & ((1 << i) - 1))][m16][0];
    dst[0] = *(const half8*)(p + q8);
    dst[1] = *(const half8*)(p + 32 + q8);
  };

  float xr[4];   // fp32 residual master (batch m16, filters col4+j)

  #pragma unroll 1
  for (int t = 0; t < T_STEPS; ++t) {
    // ---- y_{t-1}: all lanes re-derive from ypartS ----
    float yv;
    if (t == 0) yv = rInit;
    else {
      float4 yp = *(const float4*)&ypartS[m16][0];
      yv = (yp.x + yp.y + yp.z + yp.w) + rb6;
    }
    if (t > 0 && w == 0 && q == 0)
      out[(size_t)(b0 + m16) * T_STEPS + (t - 1)] = yv;   // fire-and-forget
    const float yh = (float)(h16)yv;                       // match old h16 y input

    // ---- consumer-side x0 = tanh(xFeat + w1y*y) : no barrier, no MFMA ----
    half8 xB0, xB1;
    #pragma unroll
    for (int j = 0; j < 4; ++j) {
      xB0[j]     = (h16)tanh_fast(xf0[j] + (float)w1h0[j] * yh);
      xB0[4 + j] = (h16)tanh_fast(xf1[j] + (float)w1h0[4 + j] * yh);
      xB1[j]     = (h16)tanh_fast(xf2[j] + (float)w1h1[j] * yh);
      xB1[4 + j] = (h16)tanh_fast(xf3[j] + (float)w1h1[4 + j] * yh);
    }
    #pragma unroll
    for (int j = 0; j < 4; ++j)
      xr[j] = tanh_fast(xf4[j] + (float)w1h4[j] * yh);     // owned cols, f32 master

    // prefetch next step's xFeat (consumed ~a full step later)
    if (t + 1 < T_STEPS) {
      const float* xfn = xfb + (t + 1) * F;
      xf0 = *(const float4*)(xfn + q8);      xf1 = *(const float4*)(xfn + q8 + 4);
      xf2 = *(const float4*)(xfn + 32 + q8); xf3 = *(const float4*)(xfn + 32 + q8 + 4);
      xf4 = *(const float4*)(xfn + col4);
    }

    half8 stat[2];
    loadStat(stat, 0, t);                                  // ring slot 0 (preloaded at t=0)

    floatx4 hAccA = {0.f, 0.f, 0.f, 0.f};
    floatx4 hAccB = {0.f, 0.f, 0.f, 0.f};

    #pragma unroll
    for (int i = 0; i < 6; ++i) {
      const int d = 1 << i;
      if (i > 0) {                                         // layer 0 uses register xB
        xB0 = *(const half8*)&xH[m16][q8];
        xB1 = *(const half8*)&xH[m16][32 + q8];
      }
      half8 stN[2];
      if (i < 5) loadStat(stN, i + 1, t);                  // pure-LDS prefetch

      // phase A: dil^T = W2^T stat^T + W3^T x^T (split accumulators)
      floatx4 aF0 = {0.f,0.f,0.f,0.f}, aF1 = {0.f,0.f,0.f,0.f};
      floatx4 aG0 = {0.f,0.f,0.f,0.f}, aG1 = {0.f,0.f,0.f,0.f};
      aF0 = mfma16(rW2[0][0], stat[0], aF0);
      aF1 = mfma16(rW2[0][1], stat[1], aF1);
      aG0 = mfma16(rW2[1][0], stat[0], aG0);
      aG1 = mfma16(rW2[1][1], stat[1], aG1);
      aF0 = mfma16(rW3[0][0], xB0, aF0);
      aF1 = mfma16(rW3[0][1], xB1, aF1);
      aG0 = mfma16(rW3[1][0], xB0, aG0);
      aG1 = mfma16(rW3[1][1], xB1, aG1);
      half4 gv;
      #pragma unroll
      for (int j = 0; j < 4; ++j) {
        float f = aF0[j] + aF1[j] + rb2fv[j];
        float g = aG0[j] + aG1[j] + rb2gv[j];
        gv[j] = (h16)gate_fast(f, g);
      }
      *(half4*)&gatedH[m16][col4] = gv;
      BAR();                                               // B2a: gatedH ready

      // phase B: o^T = W4^T gated^T
      half8 gB0 = *(const half8*)&gatedH[m16][q8];
      half8 gB1 = *(const half8*)&gatedH[m16][32 + q8];
      floatx4 oS0 = {0.f,0.f,0.f,0.f}, oS1 = {0.f,0.f,0.f,0.f};
      floatx4 oR0 = {0.f,0.f,0.f,0.f}, oR1 = {0.f,0.f,0.f,0.f};
      oS0 = mfma16(rW4[0][0], gB0, oS0);
      oS1 = mfma16(rW4[0][1], gB1, oS1);
      oR0 = mfma16(rW4[1][0], gB0, oR0);
      oR1 = mfma16(rW4[1][1], gB1, oR1);
      half4 sv, xv2;
      #pragma unroll
      for (int j = 0; j < 4; ++j) {
        float s = oS0[j] + oS1[j] + rb4sv[j];
        sv[j] = (h16)fmaxf(s, 0.0f);
        float xn = xr[j] + (oR0[j] + oR1[j] + rb4rv[j]);   // fp32 master update
        xr[j] = xn;
        xv2[j] = (h16)xn;
      }
      *(half4*)&skipH[m16][col4] = sv;
      *(half4*)&xH[m16][col4]   = xv2;
      if (i < 5) *(half4*)&ringL[((1 << i) - 1) + (t & (d - 1))][m16][col4] = xv2;
      BAR();                                               // B2b: skipH/xH/ring ready

      // W5 skip-chunk i (off the serial chain)
      half8 sB0 = *(const half8*)&skipH[m16][q8];
      half8 sB1 = *(const half8*)&skipH[m16][32 + q8];
      hAccA = mfma16(w5r[i][0], sB0, hAccA);
      hAccA = mfma16(w5r[i][2], sB1, hAccA);
      hAccB = mfma16(w5r[i][1], sB0, hAccB);
      hAccB = mfma16(w5r[i][3], sB1, hAccB);

      if (i < 5) { stat[0] = stN[0]; stat[1] = stN[1]; }
    }

    // ---- head: y-partial over this lane's 8 hid rows ----
    {
      float vv = 0.f;
      #pragma unroll
      for (int j = 0; j < 4; ++j) {
        vv += fmaxf(hAccA[j] + rb5av[j], 0.0f) * rw6av[j];
        vv += fmaxf(hAccB[j] + rb5bv[j], 0.0f) * rw6bv[j];
      }
      vv += __shfl_xor(vv, 16);
      vv += __shfl_xor(vv, 32);
      if (q == 0) ypartS[m16][w] = vv;
    }
    BAR();                                                 // B3: ypartS ready
  }

  // final y (t = 23)
  {
    float4 yp = *(const float4*)&ypartS[m16][0];
    float yv = (yp.x + yp.y + yp.z + yp.w) + rb6;
    if (w == 0 && q == 0)
      out[(size_t)(b0 + m16) * T_STEPS + (T_STEPS - 1)] = yv;
  }
}

extern "C" void kernel_launch(void* const* d_in, const int* in_sizes, int n_in,
                              void* d_out, int out_size, void* d_ws, size_t ws_size,
                              hipStream_t stream) {
  const float* dec_feat = (const float*)d_in[0];
  const float* dec_init = (const float*)d_in[1];
  const float* enc      = (const float*)d_in[2];
  const float* W1 = (const float*)d_in[3];
  const float* b1 = (const float*)d_in[4];
  const float* W2 = (const float*)d_in[5];
  const float* b2 = (const float*)d_in[6];
  const float* W3 = (const float*)d_in[7];
  const float* W4 = (const float*)d_in[8];
  const float* b4 = (const float*)d_in[9];
  const float* W5 = (const float*)d_in[10];
  const float* b5 = (const float*)d_in[11];
  const float* W6 = (const float*)d_in[12];
  const float* b6 = (const float*)d_in[13];
  float* out = (float*)d_out;
  h16*   wsW5 = (h16*)d_ws;
  float* wsXF = (float*)((char*)d_ws + WS_XF_BYTE);

  prep_w5<<<24, 256, 0, stream>>>(W5, wsW5);
  prep_xfeat<<<1536, 256, 0, stream>>>(dec_feat, W1, b1, wsXF);
  decoder_v13<<<dim3(B_TOT / R), dim3(BLK), 0, stream>>>(
      dec_init, enc, W1, W2, b2, W3, W4, b4, wsW5, wsXF, b5, W6, b6, out);
}